// Round 17
// baseline (530.295 us; speedup 1.0000x reference)
//
#include <hip/hip_runtime.h>
#include <math.h>

#if __has_builtin(__builtin_amdgcn_exp2f)
#define EXP2(x) __builtin_amdgcn_exp2f(x)
#else
#define EXP2(x) exp2f(x)
#endif

#define ALPHA_LRELU 0.2f
#define LOG2E 1.4426950408889634f
#define ESHIFT 6.0f
#define BIGM 1024.0f  // bit=0 -> exp2 arg < -1000 -> p = 0

constexpr int Bc = 2, Nn = 2048, Ff = 256, Hh = 8, Oo = 32;
constexpr int NBLK = 512;

typedef _Float16 f16;
typedef f16 f16x8 __attribute__((ext_vector_type(8)));
typedef f16 f16x4 __attribute__((ext_vector_type(4)));
typedef float f32x4 __attribute__((ext_vector_type(4)));
typedef unsigned long long u64;
typedef unsigned u32;

// ---------------------------------------------------------------------------
// init: zero s-buffers + barrier counters (kernel boundary -> visible).
// ---------------------------------------------------------------------------
__global__ __launch_bounds__(256) void init_kernel(float* __restrict__ sbuf,
                                                   u32* __restrict__ bar) {
    for (int g = blockIdx.x * 256 + threadIdx.x; g < 221184; g += NBLK * 256)
        sbuf[g] = 0.f;
    int g = blockIdx.x * 256 + threadIdx.x;
    if (g < 544) bar[g] = 0;
}

// ---------------------------------------------------------------------------
// Two-level grid barrier (R13-proven, rescaled): 16 groups x 32 blocks -> root.
// Monotonic counts; agent-scope atomics; threadfence release/acquire.
// All 512 blocks co-resident (launch_bounds(256,2): VGPR<=256, LDS 39KB
// -> 2 blocks/CU).
// ---------------------------------------------------------------------------
__device__ __forceinline__ void gridbar(u32* bar, int ph) {
    __syncthreads();
    if (threadIdx.x == 0) {
        __threadfence();
        u32* lv1 = bar + 32 + (blockIdx.x & 15) * 32;
        u32 old = __hip_atomic_fetch_add(lv1, 1u, __ATOMIC_RELAXED,
                                         __HIP_MEMORY_SCOPE_AGENT);
        if (old == (u32)(ph * 32 + 31))
            __hip_atomic_fetch_add(bar, 1u, __ATOMIC_RELAXED,
                                   __HIP_MEMORY_SCOPE_AGENT);
        while (__hip_atomic_load(bar, __ATOMIC_RELAXED,
                                 __HIP_MEMORY_SCOPE_AGENT) <
               (u32)(ph * 16 + 16))
            __builtin_amdgcn_s_sleep(2);
        __threadfence();
    }
    __syncthreads();
}

// ---------------------------------------------------------------------------
// GEMM phase (verbatim R16 gemm_wave): wave = 16 rows x 32 cols, full
// preload (8 A + 16 B frags). Epilogue: 2 WhFrag writes + s1/s2 atomics.
// ---------------------------------------------------------------------------
__device__ __forceinline__ void gemm_phase(
    const f16* __restrict__ Af, const f16* __restrict__ WTF,
    const float* __restrict__ pa, f16* __restrict__ WhFrag,
    float* __restrict__ s1, float* __restrict__ s2,
    int G, int Ofull, int oshift, int xb, int yb) {
    int t = threadIdx.x;
    int w = t >> 6, lane = t & 63;
    int am = lane & 15, aq = lane >> 4;
    int mt = xb * 4 + w;
    int colb = yb * 32;

    const f16* ap = Af + (size_t)(mt * 8) * 512 + lane * 8;
    const f16* bp0 = WTF + (size_t)((colb >> 4) * 8) * 512 + lane * 8;
    const f16* bp1 = bp0 + 8 * 512;

    f16x8 av[8], bv0[8], bv1[8];
#pragma unroll
    for (int c = 0; c < 8; ++c) {
        av[c] = *(const f16x8*)(ap + c * 512);
        bv0[c] = *(const f16x8*)(bp0 + c * 512);
        bv1[c] = *(const f16x8*)(bp1 + c * 512);
    }
    f32x4 acc0 = {0.f, 0.f, 0.f, 0.f}, acc1 = acc0;
#pragma unroll
    for (int c = 0; c < 8; ++c) {
        acc0 = __builtin_amdgcn_mfma_f32_16x16x32_f16(av[c], bv0[c], acc0, 0, 0, 0);
        acc1 = __builtin_amdgcn_mfma_f32_16x16x32_f16(av[c], bv1[c], acc1, 0, 0, 0);
    }

    int m0 = mt * 16;
    int b = m0 >> 11;
    int nn0 = (m0 & 2047) + aq * 4;
    int cO = (m0 & 2047) >> 5;
    int aq_p = ((mt & 1) << 1) | (aq >> 1);
    int i0p = (aq & 1) << 2;
    int g = colb >> oshift;
    size_t bg = (size_t)b * G + g;
    int cg = (colb & (Ofull - 1)) >> 4;

    f16x4 c40, c41;
#pragma unroll
    for (int e = 0; e < 4; ++e) { c40[e] = (f16)acc0[e]; c41[e] = (f16)acc1[e]; }
    *(f16x4*)&WhFrag[(((bg * (Ofull >> 4) + cg) * 64 + cO) * 512) +
                     (aq_p * 16 + am) * 8 + i0p] = c40;
    *(f16x4*)&WhFrag[(((bg * (Ofull >> 4) + cg + 1) * 64 + cO) * 512) +
                     (aq_p * 16 + am) * 8 + i0p] = c41;

    int o0 = (colb & (Ofull - 1)) + am;
    const float* a1p = pa + 2 * (size_t)g * Ofull;
    float a10 = a1p[o0], a11 = a1p[o0 + 16];
    float a20 = a1p[Ofull + o0], a21 = a1p[Ofull + o0 + 16];
#pragma unroll
    for (int e = 0; e < 4; ++e) {
        float p1 = acc0[e] * a10 + acc1[e] * a11;
        float p2 = acc0[e] * a20 + acc1[e] * a21;
#pragma unroll
        for (int s = 1; s < 16; s <<= 1) {
            p1 += __shfl_xor(p1, s);
            p2 += __shfl_xor(p2, s);
        }
        if (am == 0) {
            size_t sidx = bg * Nn + nn0 + e;
            atomicAdd(&s1[sidx], p1);
            atomicAdd(&s2[sidx], p2);
        }
    }
}

// ---------------------------------------------------------------------------
// Attention phase (R16 body, NW=4): 4 waves = 4 j-slices; each wave =
// 2 row-tiles (32 rows) x CGW*16 cols, prefetch-2, e-in-registers.
// End: barrier, 4-way j-slice LDS combine, waves 0/1 run tile epilogues.
// Trailing syncthreads so the phase can be called in a loop (LDS reuse).
// ---------------------------------------------------------------------------
template <int CGW, bool OUT, bool FINAL>
__device__ __forceinline__ void attn_phase(
    const f16* __restrict__ WhFrag, const float* __restrict__ s1,
    const float* __restrict__ s2, const u32* __restrict__ maskT,
    float* __restrict__ dst, f16* __restrict__ AfOut,
    int xb, int yq, int bz,
    float* __restrict__ LsS, float* __restrict__ AsS, f16* __restrict__ TS) {
    constexpr float C0 = -ESHIFT * LOG2E - BIGM;
    constexpr int NCG = OUT ? 16 : 2;
    constexpr int TSTR = 72;

    int t = threadIdx.x;
    int w = t >> 6, lane = t & 63;
    int am = lane & 15, aq = lane >> 4;
    int i0 = xb * 32;
    int b = OUT ? bz : (bz >> 3);
    int cg0 = OUT ? yq * CGW : 0;
    int dstcol = OUT ? cg0 * 16 : (bz & 7) * Oo;

    const f16* bp[CGW];
#pragma unroll
    for (int i = 0; i < CGW; ++i)
        bp[i] = WhFrag + ((size_t)bz * NCG + cg0 + i) * 64 * 512 + lane * 8;
    const float* s2p = s2 + (size_t)bz * Nn + aq * 8;
    float s1v0 = s1[(size_t)bz * Nn + i0 + am];
    float s1v1 = s1[(size_t)bz * Nn + i0 + 16 + am];
    const u32* mtp0 = maskT + (size_t)b * 64 * 2048 + i0 + am;
    const u32* mtp1 = mtp0 + 16;

    f32x4 acc[2][CGW] = {};
    float lacc0 = 0.f, lacc1 = 0.f;

    int cbeg = w * 16, cend = cbeg + 16;  // this wave's j-slice (16 chunks)

    f16x8 xb_[CGW], yb_[CGW];
    f32x4 xv0, xv1, yv0, yv1;
    u32 xm0, xm1, ym0, ym1;
    auto ld = [&](int c, f16x8 (&bb)[CGW], f32x4& v0, f32x4& v1,
                  u32& m0, u32& m1) {
#pragma unroll
        for (int i = 0; i < CGW; ++i) bb[i] = *(const f16x8*)(bp[i] + c * 512);
        v0 = *(const f32x4*)(s2p + c * 32);
        v1 = *(const f32x4*)(s2p + c * 32 + 4);
        m0 = mtp0[c * 2048];
        m1 = mtp1[c * 2048];
    };
    auto comp = [&](f16x8 (&bb)[CGW], f32x4 v0, f32x4 v1, u32 m0, u32 m1) {
        u32 bits0 = (m0 >> (aq * 8)) & 0xffu;
        u32 bits1 = (m1 >> (aq * 8)) & 0xffu;
        f16x8 af0, af1;
#pragma unroll
        for (int k = 0; k < 8; ++k) {
            float sv = (k < 4 ? v0[k] : v1[k - 4]);
            float x0 = s1v0 + sv;
            float x1 = s1v1 + sv;
            float lr0 = fmaxf(x0, ALPHA_LRELU * x0);
            float lr1 = fmaxf(x1, ALPHA_LRELU * x1);
            float bf0 = (float)((bits0 >> k) & 1u);
            float bf1 = (float)((bits1 >> k) & 1u);
            float p0 = EXP2(fmaf(bf0, BIGM, fmaf(lr0, LOG2E, C0)));
            float p1 = EXP2(fmaf(bf1, BIGM, fmaf(lr1, LOG2E, C0)));
            lacc0 += p0;
            lacc1 += p1;
            af0[k] = (f16)p0;
            af1[k] = (f16)p1;
        }
#pragma unroll
        for (int i = 0; i < CGW; ++i) {
            acc[0][i] = __builtin_amdgcn_mfma_f32_16x16x32_f16(af0, bb[i], acc[0][i], 0, 0, 0);
            acc[1][i] = __builtin_amdgcn_mfma_f32_16x16x32_f16(af1, bb[i], acc[1][i], 0, 0, 0);
        }
    };

    ld(cbeg, xb_, xv0, xv1, xm0, xm1);
    ld(cbeg + 1, yb_, yv0, yv1, ym0, ym1);
    for (int c = cbeg; c < cend; c += 2) {
        comp(xb_, xv0, xv1, xm0, xm1);
        ld(c + 2 < cend ? c + 2 : cbeg, xb_, xv0, xv1, xm0, xm1);
        comp(yb_, yv0, yv1, ym0, ym1);
        ld(c + 3 < cend ? c + 3 : cbeg, yb_, yv0, yv1, ym0, ym1);
    }

    // intra-wave l: sum over aq groups -> lane holds l_slice[am] per tile
    lacc0 += __shfl_xor(lacc0, 16);
    lacc0 += __shfl_xor(lacc0, 32);
    lacc1 += __shfl_xor(lacc1, 16);
    lacc1 += __shfl_xor(lacc1, 32);

    LsS[(w * 2 + 0) * 64 + lane] = lacc0;
    LsS[(w * 2 + 1) * 64 + lane] = lacc1;
#pragma unroll
    for (int tt = 0; tt < 2; ++tt)
#pragma unroll
        for (int i = 0; i < CGW; ++i)
#pragma unroll
            for (int e = 0; e < 4; ++e)
                AsS[(w * 64 + lane) * 32 + tt * CGW * 4 + i * 4 + e] =
                    acc[tt][i][e];
    __syncthreads();

    if (w < 2) {  // wave w finishes row tile tt = w
        int tt = w;
        float lt = LsS[(0 * 2 + tt) * 64 + lane] + LsS[(1 * 2 + tt) * 64 + lane] +
                   LsS[(2 * 2 + tt) * 64 + lane] + LsS[(3 * 2 + tt) * 64 + lane];
        f16* Tw = &TS[tt * 16 * TSTR];
#pragma unroll
        for (int i = 0; i < CGW; ++i) {
            f32x4 a;
#pragma unroll
            for (int e = 0; e < 4; ++e)
                a[e] = AsS[(0 * 64 + lane) * 32 + tt * CGW * 4 + i * 4 + e] +
                       AsS[(1 * 64 + lane) * 32 + tt * CGW * 4 + i * 4 + e] +
                       AsS[(2 * 64 + lane) * 32 + tt * CGW * 4 + i * 4 + e] +
                       AsS[(3 * 64 + lane) * 32 + tt * CGW * 4 + i * 4 + e];
#pragma unroll
            for (int e = 0; e < 4; ++e) {
                int r = aq * 4 + e;             // C/D: col=am, row=aq*4+e
                float li = __shfl(lt, r);       // lane r holds l[row r]
                float v = a[e] / li;
                v = v > 0.f ? v : __expf(v) - 1.f;
                if (OUT) v = v > 0.f ? v : __expf(v) - 1.f;
                if (FINAL) {
                    dst[((size_t)b * Nn + i0 + tt * 16 + r) * Ff + dstcol +
                        i * 16 + am] = v;
                } else {
                    Tw[r * TSTR + i * 16 + am] = (f16)v;
                }
            }
        }
        if (!FINAL) {
            // in-wave read-back in A-frag order (no barrier: same wave's data)
            int mt = (b * Nn + i0 + tt * 16) >> 4;  // GLOBAL row tile
#pragma unroll
            for (int s = 0; s < CGW / 2; ++s) {
                f16x8 o = *(const f16x8*)&Tw[am * TSTR + s * 32 + aq * 8];
                int c = (dstcol >> 5) + s;
                *(f16x8*)&AfOut[(size_t)(mt * 8 + c) * 512 + lane * 8] = o;
            }
        }
    }
    __syncthreads();  // LDS safe for next call in a loop
}

// ---------------------------------------------------------------------------
// Mega kernel: all 13 phases, one launch, 512 blocks all co-resident.
// launch_bounds(256, 2): VGPR cap 256 (no spills - the R13 failure mode),
// 2 blocks/CU guaranteed (LDS 39KB -> 4/CU LDS-wise).
// ---------------------------------------------------------------------------
__global__ __launch_bounds__(256, 2) void mega_kernel(
    const int* __restrict__ adj, const float* __restrict__ x,
    const float* __restrict__ W_heads, const float* __restrict__ a_heads,
    const float* __restrict__ W_out, const float* __restrict__ a_out,
    float* __restrict__ out, f16* __restrict__ Af_a, f16* __restrict__ Af_b,
    f16* __restrict__ WhFrag, u32* __restrict__ maskT, f16* __restrict__ WTF,
    float* __restrict__ sbuf, u32* __restrict__ bar) {
    __shared__ float LsS[4 * 2 * 64];    // 2 KB
    __shared__ float AsS[4 * 64 * 32];   // 32 KB
    __shared__ f16 TS[2 * 16 * 72];      // 4.5 KB

    const int B = blockIdx.x;
    const int t = threadIdx.x;
    int ph = 0;

    // ---- P0: prep (block-range partitioned; bodies = R16 prep) ----
    if (B < 384) {
        for (int idx = B * 256 + t; idx < Bc * Nn * Nn; idx += 384 * 256) {
            u64 bl = __ballot(adj[idx] != 0);
            int lane = t & 63;
            int i = (idx >> 11) & 2047;
            int b = idx >> 22;
            int c32 = ((idx & 2047) & ~63) >> 5;
            if (lane == 0)
                maskT[((size_t)b * 64 + c32) * 2048 + i] = (u32)bl;
            else if (lane == 1)
                maskT[((size_t)b * 64 + c32 + 1) * 2048 + i] = (u32)(bl >> 32);
        }
    } else if (B < 448) {
        int w = t >> 6, lane = t & 63;
        int am = lane & 15, aq = lane >> 4;
#pragma unroll
        for (int it = 0; it < 8; ++it) {
            int slot = (B - 384) * 4 + w + it * 256;
            int mt = slot >> 3, c = slot & 7;
            const float* ap = x + ((size_t)mt * 16 + am) * Ff + c * 32 + aq * 8;
            f32x4 v0 = *(const f32x4*)ap;
            f32x4 v1 = *(const f32x4*)(ap + 4);
            f16x8 o;
#pragma unroll
            for (int i = 0; i < 4; ++i) { o[i] = (f16)v0[i]; o[4 + i] = (f16)v1[i]; }
            *(f16x8*)&Af_a[(size_t)slot * 512 + lane * 8] = o;
        }
    } else {
#pragma unroll
        for (int it = 0; it < 6; ++it) {
            int unit = (B - 448) * 6 + it;  // 0..383
            int y = unit >> 6, bx = unit & 63;
            int ll = y >> 1, st = y & 1;
            int col = bx * 4 + (t >> 6);
            int k0 = (t & 63) * 4;
            const float* src;
            int stride;
            if (st == 0) {
                src = W_heads + (((size_t)ll * Hh + (col >> 5)) * Ff) * Oo + (col & 31);
                stride = Oo;
            } else {
                src = W_out + (size_t)ll * Ff * Ff + col;
                stride = Ff;
            }
            f16x4 v;
#pragma unroll
            for (int i = 0; i < 4; ++i) v[i] = (f16)src[(size_t)(k0 + i) * stride];
            int cg = col >> 4, am = col & 15;
            int c = k0 >> 5, aq = (k0 >> 3) & 3, i0 = k0 & 7;
            *(f16x4*)&WTF[(((size_t)y * 16 + cg) * 8 + c) * 512 +
                          (aq * 16 + am) * 8 + i0] = v;
        }
    }
    gridbar(bar, ph++);

    const size_t SH = (size_t)Bc * Hh * Nn;  // 32768
    const size_t SO = (size_t)Bc * Nn;       // 4096
    const size_t SL = 2 * SH + 2 * SO;

    for (int l = 0; l < 3; ++l) {
        float* s1h = sbuf + l * SL;
        float* s2h = s1h + SH;
        float* s1o = s2h + SH;
        float* s2o = s1o + SO;

        // ---- head GAT: G=8, O=32 ----
        gemm_phase(Af_a, WTF + (size_t)(2 * l) * Ff * Ff,
                   a_heads + (size_t)l * Hh * 2 * Oo, WhFrag, s1h, s2h,
                   Hh, Oo, 5, B & 63, B >> 6);
        gridbar(bar, ph++);
        for (int u = B; u < 1024; u += NBLK)
            attn_phase<2, false, false>(WhFrag, s1h, s2h, maskT, nullptr, Af_b,
                                        u & 63, 0, u >> 6, LsS, AsS, TS);
        gridbar(bar, ph++);

        // ---- out GAT: G=1, O=F=256 ----
        gemm_phase(Af_b, WTF + (size_t)(2 * l + 1) * Ff * Ff,
                   a_out + (size_t)l * 2 * Ff, WhFrag, s1o, s2o,
                   1, Ff, 8, B & 63, B >> 6);
        gridbar(bar, ph++);
        if (l == 2) {
            attn_phase<4, true, true>(WhFrag, s1o, s2o, maskT, out, nullptr,
                                      B & 63, (B >> 6) & 3, B >> 8, LsS, AsS, TS);
        } else {
            attn_phase<4, true, false>(WhFrag, s1o, s2o, maskT, nullptr, Af_a,
                                       B & 63, (B >> 6) & 3, B >> 8, LsS, AsS, TS);
            gridbar(bar, ph++);
        }
    }
}

// ---------------------------------------------------------------------------
extern "C" void kernel_launch(void* const* d_in, const int* in_sizes, int n_in,
                              void* d_out, int out_size, void* d_ws, size_t ws_size,
                              hipStream_t stream) {
    const float* x = (const float*)d_in[0];
    const int* adj = (const int*)d_in[1];
    const float* W_heads = (const float*)d_in[2];
    const float* a_heads = (const float*)d_in[3];
    const float* W_out = (const float*)d_in[4];
    const float* a_out = (const float*)d_in[5];
    float* out = (float*)d_out;

    float* ws = (float*)d_ws;
    const size_t M = (size_t)Bc * Nn * Ff;        // 1,048,576
    f16* Af_a = (f16*)ws;                         // M f16
    f16* Af_b = (f16*)(ws + M / 2);               // M f16
    f16* WhFrag = (f16*)(ws + M);                 // M f16
    u32* maskT = (u32*)(ws + 3 * M / 2);          // 1 MB
    f16* WTF = (f16*)(ws + 3 * M / 2 + M / 4);    // 6*F*F f16 = 196608 floats
    float* sbuf = ws + 3 * M / 2 + M / 4 + 196608;  // 221184 floats
    u32* bar = (u32*)(sbuf + 221184);             // 544 u32

    init_kernel<<<NBLK, 256, 0, stream>>>(sbuf, bar);
    mega_kernel<<<NBLK, 256, 0, stream>>>(
        adj, x, W_heads, a_heads, W_out, a_out, out,
        Af_a, Af_b, WhFrag, maskT, WTF, sbuf, bar);
}

// Round 18
// 276.453 us; speedup vs baseline: 1.9182x; 1.9182x over previous
//
#include <hip/hip_runtime.h>
#include <math.h>

#if __has_builtin(__builtin_amdgcn_exp2f)
#define EXP2(x) __builtin_amdgcn_exp2f(x)
#else
#define EXP2(x) exp2f(x)
#endif

#define ALPHA_LRELU 0.2f
#define LOG2E 1.4426950408889634f
#define ESHIFT 6.0f
#define BIGM 1024.0f  // bit=0 -> exp2 arg < -1000 -> p = 0

constexpr int Bc = 2, Nn = 2048, Ff = 256, Hh = 8, Oo = 32;

typedef _Float16 f16;
typedef f16 f16x8 __attribute__((ext_vector_type(8)));
typedef f16 f16x4 __attribute__((ext_vector_type(4)));
typedef float f32x4 __attribute__((ext_vector_type(4)));
typedef unsigned long long u64;
typedef unsigned u32;

// ---------------------------------------------------------------------------
// Fused prep (R14/R16, unchanged): zero s-bufs; B<768: adj->maskT; 768..895:
// apack x; 896..1023: weights -> B-frag WTF.
// ---------------------------------------------------------------------------
__global__ __launch_bounds__(256) void prep_kernel(
    const int* __restrict__ adj, const float* __restrict__ x,
    const float* __restrict__ W_heads, const float* __restrict__ W_out,
    u32* __restrict__ maskT, f16* __restrict__ Af, f16* __restrict__ WTF,
    float* __restrict__ sbuf) {
    const int B = blockIdx.x;
    const int t = threadIdx.x;
    int g = B * 256 + t;
    if (g < 221184) sbuf[g] = 0.f;  // 3 * (2*SH + 2*SO)

    if (B < 768) {
        for (int idx = g; idx < Bc * Nn * Nn; idx += 768 * 256) {
            u64 bl = __ballot(adj[idx] != 0);
            int lane = t & 63;
            int i = (idx >> 11) & 2047;
            int b = idx >> 22;
            int c32 = ((idx & 2047) & ~63) >> 5;
            if (lane == 0)
                maskT[((size_t)b * 64 + c32) * 2048 + i] = (u32)bl;
            else if (lane == 1)
                maskT[((size_t)b * 64 + c32 + 1) * 2048 + i] = (u32)(bl >> 32);
        }
    } else if (B < 896) {
        int w = t >> 6, lane = t & 63;
        int am = lane & 15, aq = lane >> 4;
#pragma unroll
        for (int it = 0; it < 4; ++it) {
            int slot = (B - 768) * 4 + w + it * 512;
            int mt = slot >> 3, c = slot & 7;
            const float* ap = x + ((size_t)mt * 16 + am) * Ff + c * 32 + aq * 8;
            f32x4 v0 = *(const f32x4*)ap;
            f32x4 v1 = *(const f32x4*)(ap + 4);
            f16x8 o;
#pragma unroll
            for (int i = 0; i < 4; ++i) { o[i] = (f16)v0[i]; o[4 + i] = (f16)v1[i]; }
            *(f16x8*)&Af[(size_t)slot * 512 + lane * 8] = o;
        }
    } else {
#pragma unroll
        for (int it = 0; it < 3; ++it) {
            int unit = (B - 896) * 3 + it;  // 0..383
            int y = unit >> 6, bx = unit & 63;
            int ll = y >> 1, st = y & 1;
            int col = bx * 4 + (t >> 6);
            int k0 = (t & 63) * 4;
            const float* src;
            int stride;
            if (st == 0) {
                src = W_heads + (((size_t)ll * Hh + (col >> 5)) * Ff) * Oo + (col & 31);
                stride = Oo;
            } else {
                src = W_out + (size_t)ll * Ff * Ff + col;
                stride = Ff;
            }
            f16x4 v;
#pragma unroll
            for (int i = 0; i < 4; ++i) v[i] = (f16)src[(size_t)(k0 + i) * stride];
            int cg = col >> 4, am = col & 15;
            int c = k0 >> 5, aq = (k0 >> 3) & 3, i0 = k0 & 7;
            *(f16x4*)&WTF[(((size_t)y * 16 + cg) * 8 + c) * 512 +
                          (aq * 16 + am) * 8 + i0] = v;
        }
    }
}

// ---------------------------------------------------------------------------
// Frag GEMM (R16, unchanged): wave = 16 rows x 32 cols, FULL-PRELOAD
// (8 A + 16 B frags). Grid (64, 8). Epilogue: 2 WhFrag writes + s1/s2 atomics.
// ---------------------------------------------------------------------------
__global__ __launch_bounds__(256) void gemm_wave(
    const f16* __restrict__ Af, const f16* __restrict__ WTF,
    const float* __restrict__ pa, f16* __restrict__ WhFrag,
    float* __restrict__ s1, float* __restrict__ s2,
    int G, int Ofull, int oshift) {
    int t = threadIdx.x;
    int w = t >> 6, lane = t & 63;
    int am = lane & 15, aq = lane >> 4;
    int mt = blockIdx.x * 4 + w;
    int colb = blockIdx.y * 32;

    const f16* ap = Af + (size_t)(mt * 8) * 512 + lane * 8;
    const f16* bp0 = WTF + (size_t)((colb >> 4) * 8) * 512 + lane * 8;
    const f16* bp1 = bp0 + 8 * 512;

    f16x8 av[8], bv0[8], bv1[8];
#pragma unroll
    for (int c = 0; c < 8; ++c) {
        av[c] = *(const f16x8*)(ap + c * 512);
        bv0[c] = *(const f16x8*)(bp0 + c * 512);
        bv1[c] = *(const f16x8*)(bp1 + c * 512);
    }
    f32x4 acc0 = {0.f, 0.f, 0.f, 0.f}, acc1 = acc0;
#pragma unroll
    for (int c = 0; c < 8; ++c) {
        acc0 = __builtin_amdgcn_mfma_f32_16x16x32_f16(av[c], bv0[c], acc0, 0, 0, 0);
        acc1 = __builtin_amdgcn_mfma_f32_16x16x32_f16(av[c], bv1[c], acc1, 0, 0, 0);
    }

    int m0 = mt * 16;
    int b = m0 >> 11;
    int nn0 = (m0 & 2047) + aq * 4;
    int cO = (m0 & 2047) >> 5;
    int aq_p = ((mt & 1) << 1) | (aq >> 1);
    int i0p = (aq & 1) << 2;
    int g = colb >> oshift;
    size_t bg = (size_t)b * G + g;
    int cg = (colb & (Ofull - 1)) >> 4;

    f16x4 c40, c41;
#pragma unroll
    for (int e = 0; e < 4; ++e) { c40[e] = (f16)acc0[e]; c41[e] = (f16)acc1[e]; }
    *(f16x4*)&WhFrag[(((bg * (Ofull >> 4) + cg) * 64 + cO) * 512) +
                     (aq_p * 16 + am) * 8 + i0p] = c40;
    *(f16x4*)&WhFrag[(((bg * (Ofull >> 4) + cg + 1) * 64 + cO) * 512) +
                     (aq_p * 16 + am) * 8 + i0p] = c41;

    int o0 = (colb & (Ofull - 1)) + am;
    const float* a1p = pa + 2 * (size_t)g * Ofull;
    float a10 = a1p[o0], a11 = a1p[o0 + 16];
    float a20 = a1p[Ofull + o0], a21 = a1p[Ofull + o0 + 16];
#pragma unroll
    for (int e = 0; e < 4; ++e) {
        float p1 = acc0[e] * a10 + acc1[e] * a11;
        float p2 = acc0[e] * a20 + acc1[e] * a21;
#pragma unroll
        for (int s = 1; s < 16; s <<= 1) {
            p1 += __shfl_xor(p1, s);
            p2 += __shfl_xor(p2, s);
        }
        if (am == 0) {
            size_t sidx = bg * Nn + nn0 + e;
            atomicAdd(&s1[sidx], p1);
            atomicAdd(&s2[sidx], p2);
        }
    }
}

// ---------------------------------------------------------------------------
// Attention (R16 structure): NW waves = (NW/4 col-halves) x (4 j-slices);
// each wave = 2 row-tiles (32 rows) x CGW*16 cols, prefetch-2,
// e-in-registers.
// NEW vs R16: l row-sums via MFMA with a ones-B operand (idle matrix pipe)
// instead of 16 scalar adds/chunk + shuffles. accl lands in C/D layout
// (l[row=aq*4+e]), col-independent -> tiny broadcast LDS table LsL written
// by ch-0 am==0 lanes only; epilogue reads it directly, no shuffles.
// Head: NW=4, CGW=2, grid (64,1,16). Out: NW=8, CGW=4, grid (64,2,2).
// ---------------------------------------------------------------------------
template <int CGW, int NW, bool OUT, bool FINAL>
__global__ __launch_bounds__(NW * 64) void attn_kernel(
    const f16* __restrict__ WhFrag, const float* __restrict__ s1,
    const float* __restrict__ s2, const u32* __restrict__ maskT,
    float* __restrict__ dst, f16* __restrict__ AfOut) {
    constexpr float C0 = -ESHIFT * LOG2E - BIGM;
    constexpr int NCG = OUT ? 16 : 2;
    constexpr int COLS = (NW / 4) * CGW * 16;  // block col coverage
    constexpr int TSTR = COLS + 8;             // f16 LDS row stride, 16B-aligned
    __shared__ float LsL[4 * 2 * 16];          // [js][tt][row] l partials
    __shared__ float As[NW][64][2 * CGW * 4];
    __shared__ f16 T[2][16 * TSTR];

    int t = threadIdx.x;
    int w = t >> 6, lane = t & 63;
    int am = lane & 15, aq = lane >> 4;
    int ch = w >> 2;   // col-half
    int js = w & 3;    // j-slice
    int i0 = blockIdx.x * 32;
    int bz = blockIdx.z;
    int b = OUT ? bz : (bz >> 3);
    int cg0 = OUT ? blockIdx.y * ((NW / 4) * CGW) + ch * CGW : 0;
    int dstcol = OUT ? cg0 * 16 : (bz & 7) * Oo;

    const f16* bp[CGW];
#pragma unroll
    for (int i = 0; i < CGW; ++i)
        bp[i] = WhFrag + ((size_t)bz * NCG + cg0 + i) * 64 * 512 + lane * 8;
    const float* s2p = s2 + (size_t)bz * Nn + aq * 8;
    float s1v0 = s1[(size_t)bz * Nn + i0 + am];
    float s1v1 = s1[(size_t)bz * Nn + i0 + 16 + am];
    const u32* mtp0 = maskT + (size_t)b * 64 * 2048 + i0 + am;
    const u32* mtp1 = mtp0 + 16;

    f32x4 acc[2][CGW] = {};
    f32x4 accl0 = {0.f, 0.f, 0.f, 0.f}, accl1 = accl0;
    f16x8 ones;
#pragma unroll
    for (int i = 0; i < 8; ++i) ones[i] = (f16)1.0f;

    int cbeg = js * 16, cend = cbeg + 16;  // this wave's j-slice (16 chunks)

    f16x8 xb[CGW], yb[CGW];
    f32x4 xv0, xv1, yv0, yv1;
    u32 xm0, xm1, ym0, ym1;
    auto ld = [&](int c, f16x8 (&bb)[CGW], f32x4& v0, f32x4& v1,
                  u32& m0, u32& m1) {
#pragma unroll
        for (int i = 0; i < CGW; ++i) bb[i] = *(const f16x8*)(bp[i] + c * 512);
        v0 = *(const f32x4*)(s2p + c * 32);
        v1 = *(const f32x4*)(s2p + c * 32 + 4);
        m0 = mtp0[c * 2048];
        m1 = mtp1[c * 2048];
    };
    auto comp = [&](f16x8 (&bb)[CGW], f32x4 v0, f32x4 v1, u32 m0, u32 m1) {
        u32 bits0 = (m0 >> (aq * 8)) & 0xffu;
        u32 bits1 = (m1 >> (aq * 8)) & 0xffu;
        f16x8 af0, af1;
#pragma unroll
        for (int k = 0; k < 8; ++k) {
            float sv = (k < 4 ? v0[k] : v1[k - 4]);
            float x0 = s1v0 + sv;
            float x1 = s1v1 + sv;
            float lr0 = fmaxf(x0, ALPHA_LRELU * x0);
            float lr1 = fmaxf(x1, ALPHA_LRELU * x1);
            float bf0 = (float)((bits0 >> k) & 1u);
            float bf1 = (float)((bits1 >> k) & 1u);
            float p0 = EXP2(fmaf(bf0, BIGM, fmaf(lr0, LOG2E, C0)));
            float p1 = EXP2(fmaf(bf1, BIGM, fmaf(lr1, LOG2E, C0)));
            af0[k] = (f16)p0;
            af1[k] = (f16)p1;
        }
#pragma unroll
        for (int i = 0; i < CGW; ++i) {
            acc[0][i] = __builtin_amdgcn_mfma_f32_16x16x32_f16(af0, bb[i], acc[0][i], 0, 0, 0);
            acc[1][i] = __builtin_amdgcn_mfma_f32_16x16x32_f16(af1, bb[i], acc[1][i], 0, 0, 0);
        }
        accl0 = __builtin_amdgcn_mfma_f32_16x16x32_f16(af0, ones, accl0, 0, 0, 0);
        accl1 = __builtin_amdgcn_mfma_f32_16x16x32_f16(af1, ones, accl1, 0, 0, 0);
    };

    ld(cbeg, xb, xv0, xv1, xm0, xm1);
    ld(cbeg + 1, yb, yv0, yv1, ym0, ym1);
    for (int c = cbeg; c < cend; c += 2) {
        comp(xb, xv0, xv1, xm0, xm1);
        ld(c + 2 < cend ? c + 2 : cbeg, xb, xv0, xv1, xm0, xm1);
        comp(yb, yv0, yv1, ym0, ym1);
        ld(c + 3 < cend ? c + 3 : cbeg, yb, yv0, yv1, ym0, ym1);
    }

    // l partials: accl[e] = l[row=aq*4+e] over this wave's j-slice (all cols
    // identical -> only ch-0, am==0 lanes store; broadcast reads later).
    if (ch == 0 && am == 0) {
#pragma unroll
        for (int e = 0; e < 4; ++e) {
            LsL[(js * 2 + 0) * 16 + aq * 4 + e] = accl0[e];
            LsL[(js * 2 + 1) * 16 + aq * 4 + e] = accl1[e];
        }
    }
#pragma unroll
    for (int tt = 0; tt < 2; ++tt)
#pragma unroll
        for (int i = 0; i < CGW; ++i)
#pragma unroll
            for (int e = 0; e < 4; ++e)
                As[w][lane][tt * CGW * 4 + i * 4 + e] = acc[tt][i][e];
    __syncthreads();

    if ((w & 3) < 2) {  // wave (ch, tt) finishes row tile tt for its cols
        int tt = w & 3;
        float li4[4];
#pragma unroll
        for (int e = 0; e < 4; ++e) {
            int r = aq * 4 + e;
            li4[e] = LsL[(0 * 2 + tt) * 16 + r] + LsL[(1 * 2 + tt) * 16 + r] +
                     LsL[(2 * 2 + tt) * 16 + r] + LsL[(3 * 2 + tt) * 16 + r];
        }
        f16* Tw = T[tt];
#pragma unroll
        for (int i = 0; i < CGW; ++i) {
            f32x4 a;
#pragma unroll
            for (int e = 0; e < 4; ++e)
                a[e] = As[ch * 4 + 0][lane][tt * CGW * 4 + i * 4 + e] +
                       As[ch * 4 + 1][lane][tt * CGW * 4 + i * 4 + e] +
                       As[ch * 4 + 2][lane][tt * CGW * 4 + i * 4 + e] +
                       As[ch * 4 + 3][lane][tt * CGW * 4 + i * 4 + e];
#pragma unroll
            for (int e = 0; e < 4; ++e) {
                float v = a[e] / li4[e];
                int r = aq * 4 + e;             // C/D: col=am, row=aq*4+e
                v = v > 0.f ? v : __expf(v) - 1.f;
                if (OUT) v = v > 0.f ? v : __expf(v) - 1.f;
                if (FINAL) {
                    dst[((size_t)b * Nn + i0 + tt * 16 + r) * Ff + dstcol +
                        i * 16 + am] = v;
                } else {
                    Tw[r * TSTR + ch * CGW * 16 + i * 16 + am] = (f16)v;
                }
            }
        }
        if (!FINAL) {
            // in-wave read-back in A-frag order (no barrier: same wave's data)
            int mt = (b * Nn + i0 + tt * 16) >> 4;  // GLOBAL row tile
#pragma unroll
            for (int s = 0; s < CGW / 2; ++s) {
                f16x8 o = *(const f16x8*)&Tw[am * TSTR + ch * CGW * 16 +
                                             s * 32 + aq * 8];
                int c = (dstcol >> 5) + s;
                *(f16x8*)&AfOut[(size_t)(mt * 8 + c) * 512 + lane * 8] = o;
            }
        }
    }
}

// ---------------------------------------------------------------------------
extern "C" void kernel_launch(void* const* d_in, const int* in_sizes, int n_in,
                              void* d_out, int out_size, void* d_ws, size_t ws_size,
                              hipStream_t stream) {
    const float* x = (const float*)d_in[0];
    const int* adj = (const int*)d_in[1];
    const float* W_heads = (const float*)d_in[2];
    const float* a_heads = (const float*)d_in[3];
    const float* W_out = (const float*)d_in[4];
    const float* a_out = (const float*)d_in[5];
    float* out = (float*)d_out;

    float* ws = (float*)d_ws;
    const size_t M = (size_t)Bc * Nn * Ff;        // 1,048,576
    f16* Af_a = (f16*)ws;                         // M f16
    f16* Af_b = (f16*)(ws + M / 2);               // M f16
    f16* WhFrag = (f16*)(ws + M);                 // M f16
    u32* maskT = (u32*)(ws + 3 * M / 2);          // 1 MB
    f16* WTF = (f16*)(ws + 3 * M / 2 + M / 4);    // 6*F*F f16 = 196608 floats
    float* sbuf = ws + 3 * M / 2 + M / 4 + 196608;
    const size_t SH = (size_t)Bc * Hh * Nn;       // 32768
    const size_t SO = (size_t)Bc * Nn;            // 4096
    const size_t SL = 2 * SH + 2 * SO;

    prep_kernel<<<1024, 256, 0, stream>>>(adj, x, W_heads, W_out,
                                          maskT, Af_a, WTF, sbuf);

    for (int l = 0; l < 3; ++l) {
        float* s1h = sbuf + l * SL;
        float* s2h = s1h + SH;
        float* s1o = s2h + SH;
        float* s2o = s1o + SO;

        // ---- head GAT: G=8, O=32 ----
        gemm_wave<<<dim3((Bc * Nn) / 64, Ff / 32), 256, 0, stream>>>(
            Af_a, WTF + (size_t)(2 * l) * Ff * Ff,
            a_heads + (size_t)l * Hh * 2 * Oo, WhFrag, s1h, s2h, Hh, Oo, 5);
        attn_kernel<2, 4, false, false><<<dim3(Nn / 32, 1, Bc * Hh), 256, 0, stream>>>(
            WhFrag, s1h, s2h, maskT, nullptr, Af_b);

        // ---- out GAT: G=1, O=F=256 ----
        gemm_wave<<<dim3((Bc * Nn) / 64, Ff / 32), 256, 0, stream>>>(
            Af_b, WTF + (size_t)(2 * l + 1) * Ff * Ff,
            a_out + (size_t)l * 2 * Ff, WhFrag, s1o, s2o, 1, Ff, 8);
        if (l == 2) {
            attn_kernel<4, 8, true, true><<<dim3(Nn / 32, Ff / 128, Bc), 512, 0, stream>>>(
                WhFrag, s1o, s2o, maskT, out, nullptr);
        } else {
            attn_kernel<4, 8, true, false><<<dim3(Nn / 32, Ff / 128, Bc), 512, 0, stream>>>(
                WhFrag, s1o, s2o, maskT, nullptr, Af_a);
        }
    }
}

// Round 19
// 263.494 us; speedup vs baseline: 2.0126x; 1.0492x over previous
//
#include <hip/hip_runtime.h>
#include <math.h>

#if __has_builtin(__builtin_amdgcn_exp2f)
#define EXP2(x) __builtin_amdgcn_exp2f(x)
#else
#define EXP2(x) exp2f(x)
#endif

#define ALPHA_LRELU 0.2f
#define LOG2E 1.4426950408889634f
#define ESHIFT 6.0f
#define BIGM 1024.0f  // bit=0 -> exp2 arg < -1000 -> p = 0

constexpr int Bc = 2, Nn = 2048, Ff = 256, Hh = 8, Oo = 32;

typedef _Float16 f16;
typedef f16 f16x8 __attribute__((ext_vector_type(8)));
typedef f16 f16x4 __attribute__((ext_vector_type(4)));
typedef float f32x4 __attribute__((ext_vector_type(4)));
typedef unsigned long long u64;
typedef unsigned u32;

// ---------------------------------------------------------------------------
// Fused prep: zero s-bufs; B<768: adj->maskT; 768..895: apack x;
// 896..1023: weights -> B-frag WTF.
// ---------------------------------------------------------------------------
__global__ __launch_bounds__(256) void prep_kernel(
    const int* __restrict__ adj, const float* __restrict__ x,
    const float* __restrict__ W_heads, const float* __restrict__ W_out,
    u32* __restrict__ maskT, f16* __restrict__ Af, f16* __restrict__ WTF,
    float* __restrict__ sbuf) {
    const int B = blockIdx.x;
    const int t = threadIdx.x;
    int g = B * 256 + t;
    if (g < 221184) sbuf[g] = 0.f;  // 3 * (2*SH + 2*SO)

    if (B < 768) {
        for (int idx = g; idx < Bc * Nn * Nn; idx += 768 * 256) {
            u64 bl = __ballot(adj[idx] != 0);
            int lane = t & 63;
            int i = (idx >> 11) & 2047;
            int b = idx >> 22;
            int c32 = ((idx & 2047) & ~63) >> 5;
            if (lane == 0)
                maskT[((size_t)b * 64 + c32) * 2048 + i] = (u32)bl;
            else if (lane == 1)
                maskT[((size_t)b * 64 + c32 + 1) * 2048 + i] = (u32)(bl >> 32);
        }
    } else if (B < 896) {
        int w = t >> 6, lane = t & 63;
        int am = lane & 15, aq = lane >> 4;
#pragma unroll
        for (int it = 0; it < 4; ++it) {
            int slot = (B - 768) * 4 + w + it * 512;
            int mt = slot >> 3, c = slot & 7;
            const float* ap = x + ((size_t)mt * 16 + am) * Ff + c * 32 + aq * 8;
            f32x4 v0 = *(const f32x4*)ap;
            f32x4 v1 = *(const f32x4*)(ap + 4);
            f16x8 o;
#pragma unroll
            for (int i = 0; i < 4; ++i) { o[i] = (f16)v0[i]; o[4 + i] = (f16)v1[i]; }
            *(f16x8*)&Af[(size_t)slot * 512 + lane * 8] = o;
        }
    } else {
#pragma unroll
        for (int it = 0; it < 3; ++it) {
            int unit = (B - 896) * 3 + it;  // 0..383
            int y = unit >> 6, bx = unit & 63;
            int ll = y >> 1, st = y & 1;
            int col = bx * 4 + (t >> 6);
            int k0 = (t & 63) * 4;
            const float* src;
            int stride;
            if (st == 0) {
                src = W_heads + (((size_t)ll * Hh + (col >> 5)) * Ff) * Oo + (col & 31);
                stride = Oo;
            } else {
                src = W_out + (size_t)ll * Ff * Ff + col;
                stride = Ff;
            }
            f16x4 v;
#pragma unroll
            for (int i = 0; i < 4; ++i) v[i] = (f16)src[(size_t)(k0 + i) * stride];
            int cg = col >> 4, am = col & 15;
            int c = k0 >> 5, aq = (k0 >> 3) & 3, i0 = k0 & 7;
            *(f16x4*)&WTF[(((size_t)y * 16 + cg) * 8 + c) * 512 +
                          (aq * 16 + am) * 8 + i0] = v;
        }
    }
}

// ---------------------------------------------------------------------------
// Frag GEMM: wave = 16 rows x 32 cols (2 cg), FULL-PRELOAD (8 A + 16 B
// frags). A-frags serve 2 col-groups. Grid (64, 8) = 512 blocks.
// Epilogue: 2 WhFrag writes + s1/s2 atomics.
// ---------------------------------------------------------------------------
__global__ __launch_bounds__(256) void gemm_wave(
    const f16* __restrict__ Af, const f16* __restrict__ WTF,
    const float* __restrict__ pa, f16* __restrict__ WhFrag,
    float* __restrict__ s1, float* __restrict__ s2,
    int G, int Ofull, int oshift) {
    int t = threadIdx.x;
    int w = t >> 6, lane = t & 63;
    int am = lane & 15, aq = lane >> 4;
    int mt = blockIdx.x * 4 + w;
    int colb = blockIdx.y * 32;

    const f16* ap = Af + (size_t)(mt * 8) * 512 + lane * 8;
    const f16* bp0 = WTF + (size_t)((colb >> 4) * 8) * 512 + lane * 8;
    const f16* bp1 = bp0 + 8 * 512;

    f16x8 av[8], bv0[8], bv1[8];
#pragma unroll
    for (int c = 0; c < 8; ++c) {
        av[c] = *(const f16x8*)(ap + c * 512);
        bv0[c] = *(const f16x8*)(bp0 + c * 512);
        bv1[c] = *(const f16x8*)(bp1 + c * 512);
    }
    f32x4 acc0 = {0.f, 0.f, 0.f, 0.f}, acc1 = acc0;
#pragma unroll
    for (int c = 0; c < 8; ++c) {
        acc0 = __builtin_amdgcn_mfma_f32_16x16x32_f16(av[c], bv0[c], acc0, 0, 0, 0);
        acc1 = __builtin_amdgcn_mfma_f32_16x16x32_f16(av[c], bv1[c], acc1, 0, 0, 0);
    }

    int m0 = mt * 16;
    int b = m0 >> 11;
    int nn0 = (m0 & 2047) + aq * 4;
    int cO = (m0 & 2047) >> 5;
    int aq_p = ((mt & 1) << 1) | (aq >> 1);
    int i0p = (aq & 1) << 2;
    int g = colb >> oshift;  // 32 cols within one g (head: colb mult of 32)
    size_t bg = (size_t)b * G + g;
    int cg = (colb & (Ofull - 1)) >> 4;

    f16x4 c40, c41;
#pragma unroll
    for (int e = 0; e < 4; ++e) { c40[e] = (f16)acc0[e]; c41[e] = (f16)acc1[e]; }
    *(f16x4*)&WhFrag[(((bg * (Ofull >> 4) + cg) * 64 + cO) * 512) +
                     (aq_p * 16 + am) * 8 + i0p] = c40;
    *(f16x4*)&WhFrag[(((bg * (Ofull >> 4) + cg + 1) * 64 + cO) * 512) +
                     (aq_p * 16 + am) * 8 + i0p] = c41;

    int o0 = (colb & (Ofull - 1)) + am;
    const float* a1p = pa + 2 * (size_t)g * Ofull;
    float a10 = a1p[o0], a11 = a1p[o0 + 16];
    float a20 = a1p[Ofull + o0], a21 = a1p[Ofull + o0 + 16];
#pragma unroll
    for (int e = 0; e < 4; ++e) {
        float p1 = acc0[e] * a10 + acc1[e] * a11;
        float p2 = acc0[e] * a20 + acc1[e] * a21;
#pragma unroll
        for (int s = 1; s < 16; s <<= 1) {
            p1 += __shfl_xor(p1, s);
            p2 += __shfl_xor(p2, s);
        }
        if (am == 0) {
            size_t sidx = bg * Nn + nn0 + e;
            atomicAdd(&s1[sidx], p1);
            atomicAdd(&s2[sidx], p2);
        }
    }
}

// ---------------------------------------------------------------------------
// Attention: NW waves = (NW/4 col-halves) x (4 j-slices); each wave =
// 2 row-tiles (32 rows) x CGW*16 cols, prefetch-2, e-in-registers.
// Head: NW=4 (256 thr), CGW=2, grid (64,1,16).
// Out:  NW=8 (512 thr), CGW=4, grid (64,2,2) -> block covers 128 cols.
// End: one barrier, 4-way j-slice LDS combine per col-half, waves with
// (w&3)<2 run the tile epilogues (scalar lacc + shuffle l, R16-proven).
// ---------------------------------------------------------------------------
template <int CGW, int NW, bool OUT, bool FINAL>
__global__ __launch_bounds__(NW * 64) void attn_kernel(
    const f16* __restrict__ WhFrag, const float* __restrict__ s1,
    const float* __restrict__ s2, const u32* __restrict__ maskT,
    float* __restrict__ dst, f16* __restrict__ AfOut) {
    constexpr float C0 = -ESHIFT * LOG2E - BIGM;
    constexpr int NCG = OUT ? 16 : 2;
    constexpr int COLS = (NW / 4) * CGW * 16;  // block col coverage
    constexpr int TSTR = COLS + 8;             // f16 LDS row stride, 16B-aligned
    __shared__ float Ls[NW][2][64];
    __shared__ float As[NW][64][2 * CGW * 4];
    __shared__ f16 T[2][16 * TSTR];

    int t = threadIdx.x;
    int w = t >> 6, lane = t & 63;
    int am = lane & 15, aq = lane >> 4;
    int ch = w >> 2;   // col-half
    int js = w & 3;    // j-slice
    int i0 = blockIdx.x * 32;
    int bz = blockIdx.z;
    int b = OUT ? bz : (bz >> 3);
    int cg0 = OUT ? blockIdx.y * ((NW / 4) * CGW) + ch * CGW : 0;
    int dstcol = OUT ? cg0 * 16 : (bz & 7) * Oo;

    const f16* bp[CGW];
#pragma unroll
    for (int i = 0; i < CGW; ++i)
        bp[i] = WhFrag + ((size_t)bz * NCG + cg0 + i) * 64 * 512 + lane * 8;
    const float* s2p = s2 + (size_t)bz * Nn + aq * 8;
    float s1v0 = s1[(size_t)bz * Nn + i0 + am];
    float s1v1 = s1[(size_t)bz * Nn + i0 + 16 + am];
    const u32* mtp0 = maskT + (size_t)b * 64 * 2048 + i0 + am;
    const u32* mtp1 = mtp0 + 16;

    f32x4 acc[2][CGW] = {};
    float lacc0 = 0.f, lacc1 = 0.f;

    int cbeg = js * 16, cend = cbeg + 16;  // this wave's j-slice (16 chunks)

    f16x8 xb[CGW], yb[CGW];
    f32x4 xv0, xv1, yv0, yv1;
    u32 xm0, xm1, ym0, ym1;
    auto ld = [&](int c, f16x8 (&bb)[CGW], f32x4& v0, f32x4& v1,
                  u32& m0, u32& m1) {
#pragma unroll
        for (int i = 0; i < CGW; ++i) bb[i] = *(const f16x8*)(bp[i] + c * 512);
        v0 = *(const f32x4*)(s2p + c * 32);
        v1 = *(const f32x4*)(s2p + c * 32 + 4);
        m0 = mtp0[c * 2048];
        m1 = mtp1[c * 2048];
    };
    auto comp = [&](f16x8 (&bb)[CGW], f32x4 v0, f32x4 v1, u32 m0, u32 m1) {
        u32 bits0 = (m0 >> (aq * 8)) & 0xffu;
        u32 bits1 = (m1 >> (aq * 8)) & 0xffu;
        f16x8 af0, af1;
#pragma unroll
        for (int k = 0; k < 8; ++k) {
            float sv = (k < 4 ? v0[k] : v1[k - 4]);
            float x0 = s1v0 + sv;
            float x1 = s1v1 + sv;
            float lr0 = fmaxf(x0, ALPHA_LRELU * x0);
            float lr1 = fmaxf(x1, ALPHA_LRELU * x1);
            float bf0 = (float)((bits0 >> k) & 1u);
            float bf1 = (float)((bits1 >> k) & 1u);
            float p0 = EXP2(fmaf(bf0, BIGM, fmaf(lr0, LOG2E, C0)));
            float p1 = EXP2(fmaf(bf1, BIGM, fmaf(lr1, LOG2E, C0)));
            lacc0 += p0;
            lacc1 += p1;
            af0[k] = (f16)p0;
            af1[k] = (f16)p1;
        }
#pragma unroll
        for (int i = 0; i < CGW; ++i) {
            acc[0][i] = __builtin_amdgcn_mfma_f32_16x16x32_f16(af0, bb[i], acc[0][i], 0, 0, 0);
            acc[1][i] = __builtin_amdgcn_mfma_f32_16x16x32_f16(af1, bb[i], acc[1][i], 0, 0, 0);
        }
    };

    ld(cbeg, xb, xv0, xv1, xm0, xm1);
    ld(cbeg + 1, yb, yv0, yv1, ym0, ym1);
    for (int c = cbeg; c < cend; c += 2) {
        comp(xb, xv0, xv1, xm0, xm1);
        ld(c + 2 < cend ? c + 2 : cbeg, xb, xv0, xv1, xm0, xm1);
        comp(yb, yv0, yv1, ym0, ym1);
        ld(c + 3 < cend ? c + 3 : cbeg, yb, yv0, yv1, ym0, ym1);
    }

    // intra-wave l: sum over aq groups -> lane holds l_slice[am] per tile
    lacc0 += __shfl_xor(lacc0, 16);
    lacc0 += __shfl_xor(lacc0, 32);
    lacc1 += __shfl_xor(lacc1, 16);
    lacc1 += __shfl_xor(lacc1, 32);

    Ls[w][0][lane] = lacc0;
    Ls[w][1][lane] = lacc1;
#pragma unroll
    for (int tt = 0; tt < 2; ++tt)
#pragma unroll
        for (int i = 0; i < CGW; ++i)
#pragma unroll
            for (int e = 0; e < 4; ++e)
                As[w][lane][tt * CGW * 4 + i * 4 + e] = acc[tt][i][e];
    __syncthreads();

    if ((w & 3) < 2) {  // wave (ch, tt=js) finishes row tile tt for its cols
        int tt = w & 3;
        float lt = Ls[ch * 4 + 0][tt][lane] + Ls[ch * 4 + 1][tt][lane] +
                   Ls[ch * 4 + 2][tt][lane] + Ls[ch * 4 + 3][tt][lane];
        f16* Tw = T[tt];
#pragma unroll
        for (int i = 0; i < CGW; ++i) {
            f32x4 a;
#pragma unroll
            for (int e = 0; e < 4; ++e)
                a[e] = As[ch * 4 + 0][lane][tt * CGW * 4 + i * 4 + e] +
                       As[ch * 4 + 1][lane][tt * CGW * 4 + i * 4 + e] +
                       As[ch * 4 + 2][lane][tt * CGW * 4 + i * 4 + e] +
                       As[ch * 4 + 3][lane][tt * CGW * 4 + i * 4 + e];
#pragma unroll
            for (int e = 0; e < 4; ++e) {
                int r = aq * 4 + e;             // C/D: col=am, row=aq*4+e
                float li = __shfl(lt, r);       // lane r holds l[row r]
                float v = a[e] / li;
                v = v > 0.f ? v : __expf(v) - 1.f;
                if (OUT) v = v > 0.f ? v : __expf(v) - 1.f;
                if (FINAL) {
                    dst[((size_t)b * Nn + i0 + tt * 16 + r) * Ff + dstcol +
                        i * 16 + am] = v;
                } else {
                    Tw[r * TSTR + ch * CGW * 16 + i * 16 + am] = (f16)v;
                }
            }
        }
        if (!FINAL) {
            // in-wave read-back in A-frag order (no barrier: same wave's data)
            int mt = (b * Nn + i0 + tt * 16) >> 4;  // GLOBAL row tile
#pragma unroll
            for (int s = 0; s < CGW / 2; ++s) {
                f16x8 o = *(const f16x8*)&Tw[am * TSTR + ch * CGW * 16 +
                                             s * 32 + aq * 8];
                int c = (dstcol >> 5) + s;
                *(f16x8*)&AfOut[(size_t)(mt * 8 + c) * 512 + lane * 8] = o;
            }
        }
    }
}

// ---------------------------------------------------------------------------
extern "C" void kernel_launch(void* const* d_in, const int* in_sizes, int n_in,
                              void* d_out, int out_size, void* d_ws, size_t ws_size,
                              hipStream_t stream) {
    const float* x = (const float*)d_in[0];
    const int* adj = (const int*)d_in[1];
    const float* W_heads = (const float*)d_in[2];
    const float* a_heads = (const float*)d_in[3];
    const float* W_out = (const float*)d_in[4];
    const float* a_out = (const float*)d_in[5];
    float* out = (float*)d_out;

    float* ws = (float*)d_ws;
    const size_t M = (size_t)Bc * Nn * Ff;        // 1,048,576
    f16* Af_a = (f16*)ws;                         // M f16
    f16* Af_b = (f16*)(ws + M / 2);               // M f16
    f16* WhFrag = (f16*)(ws + M);                 // M f16
    u32* maskT = (u32*)(ws + 3 * M / 2);          // 1 MB
    f16* WTF = (f16*)(ws + 3 * M / 2 + M / 4);    // 6*F*F f16 = 196608 floats
    float* sbuf = ws + 3 * M / 2 + M / 4 + 196608;
    const size_t SH = (size_t)Bc * Hh * Nn;       // 32768
    const size_t SO = (size_t)Bc * Nn;            // 4096
    const size_t SL = 2 * SH + 2 * SO;

    prep_kernel<<<1024, 256, 0, stream>>>(adj, x, W_heads, W_out,
                                          maskT, Af_a, WTF, sbuf);

    for (int l = 0; l < 3; ++l) {
        float* s1h = sbuf + l * SL;
        float* s2h = s1h + SH;
        float* s1o = s2h + SH;
        float* s2o = s1o + SO;

        // ---- head GAT: G=8, O=32 ----
        gemm_wave<<<dim3((Bc * Nn) / 64, Ff / 32), 256, 0, stream>>>(
            Af_a, WTF + (size_t)(2 * l) * Ff * Ff,
            a_heads + (size_t)l * Hh * 2 * Oo, WhFrag, s1h, s2h, Hh, Oo, 5);
        attn_kernel<2, 4, false, false><<<dim3(Nn / 32, 1, Bc * Hh), 256, 0, stream>>>(
            WhFrag, s1h, s2h, maskT, nullptr, Af_b);

        // ---- out GAT: G=1, O=F=256 ----
        gemm_wave<<<dim3((Bc * Nn) / 64, Ff / 32), 256, 0, stream>>>(
            Af_b, WTF + (size_t)(2 * l + 1) * Ff * Ff,
            a_out + (size_t)l * 2 * Ff, WhFrag, s1o, s2o, 1, Ff, 8);
        if (l == 2) {
            attn_kernel<4, 8, true, true><<<dim3(Nn / 32, Ff / 128, Bc), 512, 0, stream>>>(
                WhFrag, s1o, s2o, maskT, out, nullptr);
        } else {
            attn_kernel<4, 8, true, false><<<dim3(Nn / 32, Ff / 128, Bc), 512, 0, stream>>>(
                WhFrag, s1o, s2o, maskT, nullptr, Af_a);
        }
    }
}